// Round 2
// baseline (898.431 us; speedup 1.0000x reference)
//
#include <hip/hip_runtime.h>
#include <hip/hip_bf16.h>

// Continuous convolution (Open3D CConv style), fused single-pass design:
//   WG = 16 voxels (512 edges). Per CIN-chunk of 8: scatter edges into LDS
//   B tile (f32, atomics), then MFMA-contract against pre-split bf16 W.
// Accuracy: B accumulated in f32; contraction uses bf16 hi/lo split
// (3 MFMA products) so arithmetic stays ~f32-exact. Output stored as f32
// (reference output dtype is float32 — round 1 bug was storing bf16 bits).

typedef unsigned short u16;
typedef __attribute__((ext_vector_type(4))) float f32x4;
typedef __attribute__((ext_vector_type(8))) short short8;

#define NOUT    65536
#define VX      16            // voxels per workgroup
#define THREADS 512
#define EPW     512           // edges per WG (16 voxels * 32 nbrs)
#define BSTRIDE 516           // 64 bins * 8 ch + 4 pad floats (bank-conflict pad)
#define NWG     (NOUT / VX)   // 4096

// LDS carve (bytes):
//   Bl    [VX*BSTRIDE] f32          0     .. 33024
//   wa    [8][512] f32 (alias Yp)   33024 .. 49408
//   kaddr [512][8] u16              49408 .. 57600
//   fbase [512] int                 57600 .. 59648
//   den   [16] f32                  59648 .. 59712
#define SMEM_BYTES 59712

// ---- prep: split W (2048x32 f32, row-major) into transposed bf16 hi/lo ----
__global__ void prep_w_kernel(const float* __restrict__ W,
                              u16* __restrict__ wt_hi,
                              u16* __restrict__ wt_lo) {
  int t  = blockIdx.x * 256 + threadIdx.x;   // 0..65535
  int kr = t >> 5;                           // kappa 0..2047 (kv*32 + c)
  int d  = t & 31;                           // cout
  float w = W[t];
  unsigned u = __float_as_uint(w);
  u16 hi = (u16)(u >> 16);                               // truncated bf16
  float rem = w - __uint_as_float(u & 0xFFFF0000u);      // exact residual
  u16 lo = (u16)(__float_as_uint(rem) >> 16);
  wt_hi[d * 2048 + kr] = hi;   // W^T layout: [cout][kappa]
  wt_lo[d * 2048 + kr] = lo;
}

__launch_bounds__(THREADS, 4)
__global__ void cconv_kernel(const float* __restrict__ feats,
                             const float* __restrict__ inp_points,
                             const float* __restrict__ out_points,
                             const float* __restrict__ out_extents,
                             const float* __restrict__ scale_compat,
                             const int*   __restrict__ nbr_idx,
                             const int*   __restrict__ row_splits,
                             const float* __restrict__ nbr_dist,
                             const float* __restrict__ bias,
                             const u16*   __restrict__ wt_hi,
                             const u16*   __restrict__ wt_lo,
                             float*       __restrict__ out) {
  __shared__ __align__(16) char smem[SMEM_BYTES];
  float* Bl    = (float*)smem;
  float* wa    = (float*)(smem + 33024);
  float* Yp    = wa;                          // alias: reused after scatter done
  u16*   kaddr = (u16*)(smem + 49408);
  int*   fbase = (int*)(smem + 57600);
  float* den   = (float*)(smem + 59648);

  const int tid  = threadIdx.x;
  const int wg   = blockIdx.x;
  const int lane = tid & 63;
  const int wv   = tid >> 6;                  // wave 0..7

  if (tid < VX) den[tid] = 0.f;
  __syncthreads();

  // ---------------- geometry: one edge per thread ----------------
  {
    // int64-vs-int32 index detection: int32 view of int64 row_splits has a
    // zero at word 1; int32 row_splits[1] == 32.
    const bool is64 = (row_splits[1] == 0);
    int e  = tid;                 // 0..511
    int v  = e >> 5;              // voxel within WG
    int gv = (wg << 4) + v;       // global voxel
    int ge = (wg << 9) + e;       // global edge
    int idx = nbr_idx[is64 ? (ge << 1) : ge];   // low word of int64 is the value
    float dist = nbr_dist[ge];
    float sc   = scale_compat[ge];
    float om = 1.f - dist * dist;
    om = fminf(fmaxf(om, 0.f), 1.f);
    float a = sc * om * om * om;                     // importance
    float inv = 2.f / out_extents[0];
    float ox = out_points[gv * 3 + 0];
    float oy = out_points[gv * 3 + 1];
    float oz = out_points[gv * 3 + 2];
    float rx = (inp_points[idx * 3 + 0] - ox) * inv;
    float ry = (inp_points[idx * 3 + 1] - oy) * inv;
    float rz = (inp_points[idx * 3 + 2] - oz) * inv;
    float n2   = sqrtf(rx * rx + ry * ry + rz * rz + 1e-12f);
    float ninf = fmaxf(fabsf(rx), fmaxf(fabsf(ry), fabsf(rz)));
    float scl  = (ninf > 1e-8f) ? (n2 / ninf) : 0.f;
    float cx = fminf(fmaxf(rx * scl, -1.f), 1.f);
    float cy = fminf(fmaxf(ry * scl, -1.f), 1.f);
    float cz = fminf(fmaxf(rz * scl, -1.f), 1.f);
    float ux = fminf(fmaxf((cx + 1.f) * 1.5f, 0.f), 3.f);
    float uy = fminf(fmaxf((cy + 1.f) * 1.5f, 0.f), 3.f);
    float uz = fminf(fmaxf((cz + 1.f) * 1.5f, 0.f), 3.f);
    float fx = fminf(floorf(ux), 2.f);
    float fy = fminf(floorf(uy), 2.f);
    float fz = fminf(floorf(uz), 2.f);
    float tx = ux - fx, ty = uy - fy, tz = uz - fz;
    int ix = (int)fx, iy = (int)fy, iz = (int)fz;
    float X1 = tx * a, X0 = a - X1;   // fold importance into x-axis weights
    float Y1 = ty,     Y0 = 1.f - ty;
    float Z1 = tz,     Z0 = 1.f - tz;
    float p00 = X0 * Y0, p01 = X0 * Y1, p10 = X1 * Y0, p11 = X1 * Y1;
    wa[0 * EPW + e] = p00 * Z0;  wa[1 * EPW + e] = p00 * Z1;
    wa[2 * EPW + e] = p01 * Z0;  wa[3 * EPW + e] = p01 * Z1;
    wa[4 * EPW + e] = p10 * Z0;  wa[5 * EPW + e] = p10 * Z1;
    wa[6 * EPW + e] = p11 * Z0;  wa[7 * EPW + e] = p11 * Z1;
    int kb = (ix * 4 + iy) * 4 + iz;                 // corner(0,0,0) bin
    int bb = (v * BSTRIDE + (kb << 3)) << 2;         // byte offset into Bl
    // corner deltas: dz=+32B, dy=+128B, dx=+512B
    kaddr[(e << 3) + 0] = (u16)(bb);
    kaddr[(e << 3) + 1] = (u16)(bb + 32);
    kaddr[(e << 3) + 2] = (u16)(bb + 128);
    kaddr[(e << 3) + 3] = (u16)(bb + 160);
    kaddr[(e << 3) + 4] = (u16)(bb + 512);
    kaddr[(e << 3) + 5] = (u16)(bb + 544);
    kaddr[(e << 3) + 6] = (u16)(bb + 640);
    kaddr[(e << 3) + 7] = (u16)(bb + 672);
    fbase[e] = idx << 5;                             // feats row base
    atomicAdd(&den[v], a);
  }
  __syncthreads();

  f32x4 acc0 = {0.f, 0.f, 0.f, 0.f};   // cout 0..15 tile
  f32x4 acc1 = {0.f, 0.f, 0.f, 0.f};   // cout 16..31 tile

  // ---------------- 4 chunks of 8 input channels ----------------
  for (int ch = 0; ch < 4; ++ch) {
    // zero B tile
    {
      f32x4 z = {0.f, 0.f, 0.f, 0.f};
      for (int i = tid; i < (VX * BSTRIDE / 4); i += THREADS)
        ((f32x4*)Bl)[i] = z;
    }
    __syncthreads();
    const int cbase = ch << 3;

    // scatter: item = (edge, channel-of-8)
    for (int it = 0; it < 8; ++it) {
      int item = (it << 9) + tid;      // 0..4095
      int e = item >> 3;
      int c = item & 7;
      float fg = feats[fbase[e] + cbase + c];
      uint4 ka = ((const uint4*)kaddr)[e];
      char* bp = (char*)Bl + (c << 2);
      float w;
      w = wa[0 * EPW + e]; if (w != 0.f) atomicAdd((float*)(bp + (ka.x & 0xFFFFu)), w * fg);
      w = wa[1 * EPW + e]; if (w != 0.f) atomicAdd((float*)(bp + (ka.x >> 16)),     w * fg);
      w = wa[2 * EPW + e]; if (w != 0.f) atomicAdd((float*)(bp + (ka.y & 0xFFFFu)), w * fg);
      w = wa[3 * EPW + e]; if (w != 0.f) atomicAdd((float*)(bp + (ka.y >> 16)),     w * fg);
      w = wa[4 * EPW + e]; if (w != 0.f) atomicAdd((float*)(bp + (ka.z & 0xFFFFu)), w * fg);
      w = wa[5 * EPW + e]; if (w != 0.f) atomicAdd((float*)(bp + (ka.z >> 16)),     w * fg);
      w = wa[6 * EPW + e]; if (w != 0.f) atomicAdd((float*)(bp + (ka.w & 0xFFFFu)), w * fg);
      w = wa[7 * EPW + e]; if (w != 0.f) atomicAdd((float*)(bp + (ka.w >> 16)),     w * fg);
    }
    __syncthreads();

    // MFMA partial contraction: wave wv owns kv in [8*wv, 8*wv+8)
    {
      int v16 = lane & 15;
      int q   = lane >> 4;
      const float* arow = Bl + v16 * BSTRIDE;
      #pragma unroll
      for (int ks = 0; ks < 2; ++ks) {
        int kv = (wv << 3) + (ks << 2) + q;
        const float* ap = arow + (kv << 3);
        f32x4 a0 = *(const f32x4*)ap;          // c 0..3
        f32x4 a1 = *(const f32x4*)(ap + 4);    // c 4..7
        short8 ahi, alo;
        #pragma unroll
        for (int j = 0; j < 4; ++j) {
          unsigned u0 = __float_as_uint(a0[j]);
          ahi[j] = (short)(u0 >> 16);
          float r0 = a0[j] - __uint_as_float(u0 & 0xFFFF0000u);
          alo[j] = (short)(__float_as_uint(r0) >> 16);
          unsigned u1 = __float_as_uint(a1[j]);
          ahi[j + 4] = (short)(u1 >> 16);
          float r1 = a1[j] - __uint_as_float(u1 & 0xFFFF0000u);
          alo[j + 4] = (short)(__float_as_uint(r1) >> 16);
        }
        int krow = (kv << 5) + cbase;          // kappa = kv*32 + c_full
        {
          int d = v16;
          short8 wh = *(const short8*)(wt_hi + d * 2048 + krow);
          short8 wl = *(const short8*)(wt_lo + d * 2048 + krow);
          acc0 = __builtin_amdgcn_mfma_f32_16x16x32_bf16(ahi, wh, acc0, 0, 0, 0);
          acc0 = __builtin_amdgcn_mfma_f32_16x16x32_bf16(ahi, wl, acc0, 0, 0, 0);
          acc0 = __builtin_amdgcn_mfma_f32_16x16x32_bf16(alo, wh, acc0, 0, 0, 0);
        }
        {
          int d = v16 + 16;
          short8 wh = *(const short8*)(wt_hi + d * 2048 + krow);
          short8 wl = *(const short8*)(wt_lo + d * 2048 + krow);
          acc1 = __builtin_amdgcn_mfma_f32_16x16x32_bf16(ahi, wh, acc1, 0, 0, 0);
          acc1 = __builtin_amdgcn_mfma_f32_16x16x32_bf16(ahi, wl, acc1, 0, 0, 0);
          acc1 = __builtin_amdgcn_mfma_f32_16x16x32_bf16(alo, wh, acc1, 0, 0, 0);
        }
      }
    }
    __syncthreads();
  }

  // ---------------- per-wave partials -> reduce -> store ----------------
  {
    // C/D layout (16x16x32): col = lane&15, row = (lane>>4)*4 + reg
    float* yp = Yp + (wv << 9);
    int v0 = (lane >> 4) << 2;
    int d0 = lane & 15;
    #pragma unroll
    for (int r = 0; r < 4; ++r) {
      yp[(v0 + r) * 32 + d0]      = acc0[r];
      yp[(v0 + r) * 32 + 16 + d0] = acc1[r];
    }
  }
  __syncthreads();
  {
    float s = 0.f;
    #pragma unroll
    for (int w = 0; w < 8; ++w) s += Yp[(w << 9) + tid];
    int v = tid >> 5;
    int d = tid & 31;
    float dn = fmaxf(den[v], 1e-8f);
    float y = s / dn + bias[d];
    out[(wg << 9) + tid] = fmaxf(y, 0.f);   // f32 output, matches reference dtype
  }
}

extern "C" void kernel_launch(void* const* d_in, const int* in_sizes, int n_in,
                              void* d_out, int out_size, void* d_ws, size_t ws_size,
                              hipStream_t stream) {
  const float* feats        = (const float*)d_in[0];
  const float* inp_points   = (const float*)d_in[1];
  const float* out_points   = (const float*)d_in[2];
  const float* out_extents  = (const float*)d_in[3];
  const float* scale_compat = (const float*)d_in[4];
  const int*   nbr_idx      = (const int*)d_in[5];
  const int*   row_splits   = (const int*)d_in[6];
  const float* nbr_dist     = (const float*)d_in[7];
  const float* W            = (const float*)d_in[8];
  const float* bias         = (const float*)d_in[9];

  u16* wt_hi = (u16*)d_ws;              // [32][2048] bf16
  u16* wt_lo = wt_hi + 2048 * 32;       // [32][2048] bf16   (256 KiB total)

  prep_w_kernel<<<256, 256, 0, stream>>>(W, wt_hi, wt_lo);
  cconv_kernel<<<NWG, THREADS, 0, stream>>>(feats, inp_points, out_points,
                                            out_extents, scale_compat, nbr_idx,
                                            row_splits, nbr_dist, bias,
                                            wt_hi, wt_lo, (float*)d_out);
}

// Round 3
// 648.726 us; speedup vs baseline: 1.3849x; 1.3849x over previous
//
#include <hip/hip_runtime.h>
#include <hip/hip_bf16.h>

// Continuous convolution, single-pass fused design (round 3):
//   WG = 8 voxels (256 edges), 512 threads, dynamic LDS 80 KB (2 WG/CU).
//   Full-channel B tile: each edge's 32-ch feats row gathered ONCE (was 4x).
//   Scatter: item=(edge, channel); 32 lanes of a half-wave = one edge's full
//   row -> LDS atomic banks (4v+c)%32 are conflict-free; corner list is
//   pre-compacted (zero weights dropped) in the geometry phase.
//   Contraction: bf16 hi/lo split MFMA (3 products) vs pre-split W^T tables.

typedef unsigned short u16;
typedef unsigned int   u32;
typedef __attribute__((ext_vector_type(4))) float f32x4;
typedef __attribute__((ext_vector_type(8))) short short8;

#define NOUT    65536
#define VX      8               // voxels per WG
#define THREADS 512
#define EPW     256             // edges per WG
#define NWG     (NOUT / VX)     // 8192
#define BSTRIDE 2052            // f32 words per voxel (64 bins * 32 ch + 4 pad)
#define VROWB   (BSTRIDE * 4)   // 8208 bytes
#define BL_BYTES (VX * VROWB)   // 65664

// LDS carve (bytes):
#define OFF_W   BL_BYTES              // wls [8][256] f32   (alias Yp 8KB)
#define OFF_D   (OFF_W + 8*EPW*4)     // dlt [8][256] u16
#define OFF_BCA (OFF_D + 8*EPW*2)     // bca [256] u32 (bb | nc<<16)
#define OFF_FB  (OFF_BCA + EPW*4)     // fbase [256] int
#define OFF_DEN (OFF_FB + EPW*4)      // den [8] f32
#define SMEM_BYTES (OFF_DEN + 64)     // 80064

// ---- prep: split W (2048x32 f32) into transposed bf16 hi/lo tables ----
__global__ void prep_w_kernel(const float* __restrict__ W,
                              u16* __restrict__ wt_hi,
                              u16* __restrict__ wt_lo) {
  int t  = blockIdx.x * 256 + threadIdx.x;   // 0..65535
  int kr = t >> 5;                           // kappa = bin*32 + c
  int d  = t & 31;                           // cout
  float w = W[t];
  unsigned u = __float_as_uint(w);
  u16 hi = (u16)(u >> 16);                              // truncated bf16
  float rem = w - __uint_as_float(u & 0xFFFF0000u);     // exact residual
  u16 lo = (u16)(__float_as_uint(rem) >> 16);
  wt_hi[d * 2048 + kr] = hi;   // W^T: [cout][kappa]
  wt_lo[d * 2048 + kr] = lo;
}

__launch_bounds__(THREADS, 4)
__global__ void cconv_kernel(const float* __restrict__ feats,
                             const float* __restrict__ inp_points,
                             const float* __restrict__ out_points,
                             const float* __restrict__ out_extents,
                             const float* __restrict__ scale_compat,
                             const int*   __restrict__ nbr_idx,
                             const int*   __restrict__ row_splits,
                             const float* __restrict__ nbr_dist,
                             const float* __restrict__ bias,
                             const u16*   __restrict__ wt_hi,
                             const u16*   __restrict__ wt_lo,
                             float*       __restrict__ out) {
  extern __shared__ __align__(16) char smem[];
  float* wls   = (float*)(smem + OFF_W);
  float* Yp    = wls;                         // alias after scatter done
  u16*   dlt   = (u16*)(smem + OFF_D);
  u32*   bca   = (u32*)(smem + OFF_BCA);
  int*   fbase = (int*)(smem + OFF_FB);
  float* den   = (float*)(smem + OFF_DEN);

  const int tid  = threadIdx.x;
  const int wg   = blockIdx.x;
  const int lane = tid & 63;
  const int wv   = tid >> 6;                  // wave 0..7

  // ---- zero B tile (all threads) ----
  {
    f32x4 z = {0.f, 0.f, 0.f, 0.f};
    for (int i = tid; i < (BL_BYTES / 16); i += THREADS)
      ((f32x4*)smem)[i] = z;
  }
  if (tid < VX) den[tid] = 0.f;

  // ---- geometry: one edge per thread (threads 0..255) ----
  if (tid < EPW) {
    const bool is64 = (row_splits[1] == 0);   // int32 view of int64 splits
    int e  = tid;
    int v  = e >> 5;
    int gv = (wg << 3) + v;
    int ge = (wg << 8) + e;
    int idx = nbr_idx[is64 ? (ge << 1) : ge];
    float dist = nbr_dist[ge];
    float sc   = scale_compat[ge];
    float om = 1.f - dist * dist;
    om = fminf(fmaxf(om, 0.f), 1.f);
    float a = sc * om * om * om;
    float inv = 2.f / out_extents[0];
    float ox = out_points[gv * 3 + 0];
    float oy = out_points[gv * 3 + 1];
    float oz = out_points[gv * 3 + 2];
    float rx = (inp_points[idx * 3 + 0] - ox) * inv;
    float ry = (inp_points[idx * 3 + 1] - oy) * inv;
    float rz = (inp_points[idx * 3 + 2] - oz) * inv;
    float n2   = sqrtf(rx * rx + ry * ry + rz * rz + 1e-12f);
    float ninf = fmaxf(fabsf(rx), fmaxf(fabsf(ry), fabsf(rz)));
    float scl  = (ninf > 1e-8f) ? (n2 / ninf) : 0.f;
    float cx = fminf(fmaxf(rx * scl, -1.f), 1.f);
    float cy = fminf(fmaxf(ry * scl, -1.f), 1.f);
    float cz = fminf(fmaxf(rz * scl, -1.f), 1.f);
    float ux = fminf(fmaxf((cx + 1.f) * 1.5f, 0.f), 3.f);
    float uy = fminf(fmaxf((cy + 1.f) * 1.5f, 0.f), 3.f);
    float uz = fminf(fmaxf((cz + 1.f) * 1.5f, 0.f), 3.f);
    float fx = fminf(floorf(ux), 2.f);
    float fy = fminf(floorf(uy), 2.f);
    float fz = fminf(floorf(uz), 2.f);
    float tx = ux - fx, ty = uy - fy, tz = uz - fz;
    int ix = (int)fx, iy = (int)fy, iz = (int)fz;
    float X1 = tx * a, X0 = a - X1;           // fold importance into x weights
    float Y1 = ty,     Y0 = 1.f - ty;
    float Z1 = tz,     Z0 = 1.f - tz;
    float p00 = X0 * Y0, p01 = X0 * Y1, p10 = X1 * Y0, p11 = X1 * Y1;
    float wc[8];
    wc[0] = p00 * Z0; wc[1] = p00 * Z1; wc[2] = p01 * Z0; wc[3] = p01 * Z1;
    wc[4] = p10 * Z0; wc[5] = p10 * Z1; wc[6] = p11 * Z0; wc[7] = p11 * Z1;
    // corner byte deltas in Bl: dz=+128, dy=+512, dx=+2048
    const int DLT[8] = {0, 128, 512, 640, 2048, 2176, 2560, 2688};
    int kb = (ix * 4 + iy) * 4 + iz;          // base bin (<=42)
    u32 bb = (u32)(v * VROWB + (kb << 7));    // <= 62832, fits u16
    int nc = 0;
    #pragma unroll
    for (int k = 0; k < 8; ++k) {
      if (wc[k] != 0.f) {
        wls[nc * EPW + e] = wc[k];
        dlt[nc * EPW + e] = (u16)DLT[k];
        ++nc;
      }
    }
    bca[e]   = bb | ((u32)nc << 16);
    fbase[e] = idx << 5;
    atomicAdd(&den[v], a);
  }
  __syncthreads();

  // ---- scatter: item = (edge, channel); half-wave = one edge row ----
  {
    const int c  = tid & 31;
    const int e0 = tid >> 5;                  // 0..15
    float fg[16];
    u32   bcn[16];
    #pragma unroll
    for (int it = 0; it < 16; ++it) {         // 16 independent gathers in flight
      int e = (it << 4) + e0;
      bcn[it] = bca[e];
      fg[it]  = feats[fbase[e] + c];
    }
    #pragma unroll
    for (int it = 0; it < 16; ++it) {
      int e   = (it << 4) + e0;
      u32 m   = bcn[it];
      int nc  = (int)(m >> 16);
      u32 base = (m & 0xFFFFu) + ((u32)c << 2);
      float f = fg[it];
      for (int j = 0; j < nc; ++j) {          // broadcast reads, ~2-3 iters
        float w = wls[j * EPW + e];
        u32   d = dlt[j * EPW + e];
        atomicAdd((float*)(smem + base + d), w * f);
      }
    }
  }
  __syncthreads();

  // ---- MFMA contraction: wave wv owns bins [8*wv, 8*wv+8) ----
  f32x4 acc0 = {0.f, 0.f, 0.f, 0.f};          // cout 0..15
  f32x4 acc1 = {0.f, 0.f, 0.f, 0.f};          // cout 16..31
  {
    int v16 = lane & 15;                      // A row (rows 8-15 dup of 0-7)
    int q   = lane >> 4;
    const char* arow = smem + (size_t)(v16 & 7) * VROWB;
    #pragma unroll
    for (int b = 0; b < 8; ++b) {
      int bin = (wv << 3) + b;
      const float* ap = (const float*)(arow + (bin << 7) + (q << 5));
      f32x4 a0 = *(const f32x4*)ap;           // ch k0..k0+3
      f32x4 a1 = *(const f32x4*)(ap + 4);     // ch k0+4..k0+7
      short8 ahi, alo;
      #pragma unroll
      for (int j = 0; j < 4; ++j) {
        unsigned u0 = __float_as_uint(a0[j]);
        ahi[j] = (short)(u0 >> 16);
        float r0 = a0[j] - __uint_as_float(u0 & 0xFFFF0000u);
        alo[j] = (short)(__float_as_uint(r0) >> 16);
        unsigned u1 = __float_as_uint(a1[j]);
        ahi[j + 4] = (short)(u1 >> 16);
        float r1 = a1[j] - __uint_as_float(u1 & 0xFFFF0000u);
        alo[j + 4] = (short)(__float_as_uint(r1) >> 16);
      }
      int krow = (bin << 5) + (q << 3);       // kappa base for this lane
      {
        int d = v16;
        short8 wh = *(const short8*)(wt_hi + d * 2048 + krow);
        short8 wl = *(const short8*)(wt_lo + d * 2048 + krow);
        acc0 = __builtin_amdgcn_mfma_f32_16x16x32_bf16(ahi, wh, acc0, 0, 0, 0);
        acc0 = __builtin_amdgcn_mfma_f32_16x16x32_bf16(ahi, wl, acc0, 0, 0, 0);
        acc0 = __builtin_amdgcn_mfma_f32_16x16x32_bf16(alo, wh, acc0, 0, 0, 0);
      }
      {
        int d = v16 + 16;
        short8 wh = *(const short8*)(wt_hi + d * 2048 + krow);
        short8 wl = *(const short8*)(wt_lo + d * 2048 + krow);
        acc1 = __builtin_amdgcn_mfma_f32_16x16x32_bf16(ahi, wh, acc1, 0, 0, 0);
        acc1 = __builtin_amdgcn_mfma_f32_16x16x32_bf16(ahi, wl, acc1, 0, 0, 0);
        acc1 = __builtin_amdgcn_mfma_f32_16x16x32_bf16(alo, wh, acc1, 0, 0, 0);
      }
    }
  }
  __syncthreads();   // scatter wls reads done everywhere; safe to alias Yp

  // ---- per-wave partials (valid C rows 0..7 live in lanes 0..31) ----
  {
    // C/D: col = lane&15, row = (lane>>4)*4 + reg
    if (lane < 32) {
      float* yp = Yp + (wv << 8);             // 8 v x 32 d per wave
      int v0 = (lane >> 4) << 2;
      int d0 = lane & 15;
      #pragma unroll
      for (int r = 0; r < 4; ++r) {
        yp[(v0 + r) * 32 + d0]      = acc0[r];
        yp[(v0 + r) * 32 + 16 + d0] = acc1[r];
      }
    }
  }
  __syncthreads();

  // ---- reduce 8 wave-partials, normalize, bias, relu, store ----
  if (tid < EPW) {
    float s = 0.f;
    #pragma unroll
    for (int w = 0; w < 8; ++w) s += Yp[(w << 8) + tid];
    int v = tid >> 5;
    int d = tid & 31;
    float dn = fmaxf(den[v], 1e-8f);
    float y = s / dn + bias[d];
    out[(wg << 8) + tid] = fmaxf(y, 0.f);
  }
}

extern "C" void kernel_launch(void* const* d_in, const int* in_sizes, int n_in,
                              void* d_out, int out_size, void* d_ws, size_t ws_size,
                              hipStream_t stream) {
  const float* feats        = (const float*)d_in[0];
  const float* inp_points   = (const float*)d_in[1];
  const float* out_points   = (const float*)d_in[2];
  const float* out_extents  = (const float*)d_in[3];
  const float* scale_compat = (const float*)d_in[4];
  const int*   nbr_idx      = (const int*)d_in[5];
  const int*   row_splits   = (const int*)d_in[6];
  const float* nbr_dist     = (const float*)d_in[7];
  const float* W            = (const float*)d_in[8];
  const float* bias         = (const float*)d_in[9];

  u16* wt_hi = (u16*)d_ws;              // [32][2048] bf16
  u16* wt_lo = wt_hi + 2048 * 32;       // [32][2048] bf16

  // allow >64KB dynamic LDS (80 KB per WG, 2 WG/CU)
  static_assert(SMEM_BYTES <= 81920, "LDS over 2-per-CU budget");
  (void)hipFuncSetAttribute((const void*)cconv_kernel,
                            hipFuncAttributeMaxDynamicSharedMemorySize,
                            SMEM_BYTES);

  prep_w_kernel<<<256, 256, 0, stream>>>(W, wt_hi, wt_lo);
  cconv_kernel<<<NWG, THREADS, SMEM_BYTES, stream>>>(
      feats, inp_points, out_points, out_extents, scale_compat, nbr_idx,
      row_splits, nbr_dist, bias, wt_hi, wt_lo, (float*)d_out);
}

// Round 4
// 638.087 us; speedup vs baseline: 1.4080x; 1.0167x over previous
//
#include <hip/hip_runtime.h>
#include <hip/hip_bf16.h>

// Continuous convolution, single-pass fused design (round 4):
//   WG = 4 voxels (128 edges), 512 threads, LDS ~38 KB -> 4 WG/CU (32 waves).
//   Gather: float4 per thread (4 ch of one edge), 2 independent loads issued
//   before the atomic loop. Corner deltas recomputed from a bitmask (no dlt
//   array). den via shfl reduction (fixes r3 zero-vs-atomic race).
//   Contraction: bf16 hi/lo split MFMA (3 products) vs pre-split W^T tables.

typedef unsigned short u16;
typedef unsigned int   u32;
typedef __attribute__((ext_vector_type(4))) float f32x4;
typedef __attribute__((ext_vector_type(8))) short short8;

#define NOUT    65536
#define VX      4               // voxels per WG
#define THREADS 512
#define EPW     128             // edges per WG
#define NWG     (NOUT / VX)     // 16384
#define BSTRIDE 2052            // f32 words per voxel (64 bins * 32 ch + 4 pad)
#define VROWB   (BSTRIDE * 4)   // 8208 bytes
#define BL_BYTES (VX * VROWB)   // 32832

// LDS carve (bytes):
#define OFF_W   BL_BYTES              // wls [8][128] f32  (alias Yp 4KB)
#define OFF_BCA (OFF_W + 8*EPW*4)     // bca [128] u32 (bb | mask<<16 | nc<<24)
#define OFF_FB  (OFF_BCA + EPW*4)     // fbase [128] int
#define OFF_DEN (OFF_FB + EPW*4)      // den [4] f32
#define SMEM_BYTES (OFF_DEN + 16)     // 37968

// ---- prep: split W (2048x32 f32) into transposed bf16 hi/lo tables ----
__global__ void prep_w_kernel(const float* __restrict__ W,
                              u16* __restrict__ wt_hi,
                              u16* __restrict__ wt_lo) {
  int t  = blockIdx.x * 256 + threadIdx.x;   // 0..65535
  int kr = t >> 5;                           // kappa = bin*32 + c
  int d  = t & 31;                           // cout
  float w = W[t];
  unsigned u = __float_as_uint(w);
  u16 hi = (u16)(u >> 16);                              // truncated bf16
  float rem = w - __uint_as_float(u & 0xFFFF0000u);     // exact residual
  u16 lo = (u16)(__float_as_uint(rem) >> 16);
  wt_hi[d * 2048 + kr] = hi;   // W^T: [cout][kappa]
  wt_lo[d * 2048 + kr] = lo;
}

__launch_bounds__(THREADS, 8)   // force VGPR<=64 so 4 WGs/CU fit wave slots
__global__ void cconv_kernel(const float* __restrict__ feats,
                             const float* __restrict__ inp_points,
                             const float* __restrict__ out_points,
                             const float* __restrict__ out_extents,
                             const float* __restrict__ scale_compat,
                             const int*   __restrict__ nbr_idx,
                             const int*   __restrict__ row_splits,
                             const float* __restrict__ nbr_dist,
                             const float* __restrict__ bias,
                             const u16*   __restrict__ wt_hi,
                             const u16*   __restrict__ wt_lo,
                             float*       __restrict__ out) {
  extern __shared__ __align__(16) char smem[];
  float* wls   = (float*)(smem + OFF_W);
  float* Yp    = wls;                         // alias after scatter done
  u32*   bca   = (u32*)(smem + OFF_BCA);
  int*   fbase = (int*)(smem + OFF_FB);
  float* den   = (float*)(smem + OFF_DEN);

  const int tid  = threadIdx.x;
  const int wg   = blockIdx.x;
  const int lane = tid & 63;
  const int wv   = tid >> 6;                  // wave 0..7

  // ---- zero B tile (all threads) ----
  {
    f32x4 z = {0.f, 0.f, 0.f, 0.f};
    for (int i = tid; i < (BL_BYTES / 16); i += THREADS)
      ((f32x4*)smem)[i] = z;
  }

  // ---- geometry: one edge per thread (threads 0..127) ----
  if (tid < EPW) {
    const bool is64 = (row_splits[1] == 0);   // int32 view of int64 splits
    int e  = tid;
    int v  = e >> 5;
    int gv = (wg << 2) + v;
    int ge = (wg << 7) + e;
    int idx = nbr_idx[is64 ? (ge << 1) : ge];
    float dist = nbr_dist[ge];
    float sc   = scale_compat[ge];
    float om = 1.f - dist * dist;
    om = fminf(fmaxf(om, 0.f), 1.f);
    float a = sc * om * om * om;
    float inv = 2.f / out_extents[0];
    float ox = out_points[gv * 3 + 0];
    float oy = out_points[gv * 3 + 1];
    float oz = out_points[gv * 3 + 2];
    float rx = (inp_points[idx * 3 + 0] - ox) * inv;
    float ry = (inp_points[idx * 3 + 1] - oy) * inv;
    float rz = (inp_points[idx * 3 + 2] - oz) * inv;
    float n2   = sqrtf(rx * rx + ry * ry + rz * rz + 1e-12f);
    float ninf = fmaxf(fabsf(rx), fmaxf(fabsf(ry), fabsf(rz)));
    float scl  = (ninf > 1e-8f) ? (n2 / ninf) : 0.f;
    float cx = fminf(fmaxf(rx * scl, -1.f), 1.f);
    float cy = fminf(fmaxf(ry * scl, -1.f), 1.f);
    float cz = fminf(fmaxf(rz * scl, -1.f), 1.f);
    float ux = fminf(fmaxf((cx + 1.f) * 1.5f, 0.f), 3.f);
    float uy = fminf(fmaxf((cy + 1.f) * 1.5f, 0.f), 3.f);
    float uz = fminf(fmaxf((cz + 1.f) * 1.5f, 0.f), 3.f);
    float fx = fminf(floorf(ux), 2.f);
    float fy = fminf(floorf(uy), 2.f);
    float fz = fminf(floorf(uz), 2.f);
    float tx = ux - fx, ty = uy - fy, tz = uz - fz;
    int ix = (int)fx, iy = (int)fy, iz = (int)fz;
    float X1 = tx * a, X0 = a - X1;           // fold importance into x weights
    float Y1 = ty,     Y0 = 1.f - ty;
    float Z1 = tz,     Z0 = 1.f - tz;
    float p00 = X0 * Y0, p01 = X0 * Y1, p10 = X1 * Y0, p11 = X1 * Y1;
    float wc[8];
    wc[0] = p00 * Z0; wc[1] = p00 * Z1; wc[2] = p01 * Z0; wc[3] = p01 * Z1;
    wc[4] = p10 * Z0; wc[5] = p10 * Z1; wc[6] = p11 * Z0; wc[7] = p11 * Z1;
    int kb = (ix * 4 + iy) * 4 + iz;          // base bin (<=42)
    u32 bb = (u32)(v * VROWB + (kb << 7));    // < 32768
    int nc = 0; u32 mask = 0;
    #pragma unroll
    for (int k = 0; k < 8; ++k) {
      if (wc[k] != 0.f) {
        wls[nc * EPW + e] = wc[k];
        mask |= (1u << k);
        ++nc;
      }
    }
    bca[e]   = bb | (mask << 16) | ((u32)nc << 24);
    fbase[e] = idx << 5;
    // per-voxel denom: half-wave (32 lanes = 1 voxel) shuffle reduction
    float s = a;
    s += __shfl_xor(s, 1);
    s += __shfl_xor(s, 2);
    s += __shfl_xor(s, 4);
    s += __shfl_xor(s, 8);
    s += __shfl_xor(s, 16);
    if ((lane & 31) == 0) den[v] = s;
  }
  __syncthreads();

  // ---- scatter: item = (edge, 4-channel group); 2 items per thread ----
  {
    const int c4 = (tid & 7) << 2;            // channel group base
    const int eA = (tid >> 3);                // 0..63
    const int eB = eA + 64;
    u32 mA = bca[eA], mB = bca[eB];
    int fA = fbase[eA], fB = fbase[eB];
    f32x4 gA = *(const f32x4*)&feats[fA + c4];    // both loads in flight
    f32x4 gB = *(const f32x4*)&feats[fB + c4];
    #pragma unroll 2
    for (int it = 0; it < 2; ++it) {
      int   e    = it ? eB : eA;
      u32   m    = it ? mB : mA;
      f32x4 g    = it ? gB : gA;
      u32   base = (m & 0xFFFFu) + ((u32)c4 << 2);
      u32   mask = (m >> 16) & 0xFFu;
      int   nc   = (int)(m >> 24);
      for (int j = 0; j < nc; ++j) {          // ~2-3 iters, uniform per edge
        float w = wls[j * EPW + e];
        int   k = __builtin_ctz(mask);
        mask &= mask - 1;
        u32 d = ((k & 1) << 7) | ((k & 2) << 8) | ((k & 4) << 9);
        float* p = (float*)(smem + base + d);
        atomicAdd(p + 0, w * g[0]);
        atomicAdd(p + 1, w * g[1]);
        atomicAdd(p + 2, w * g[2]);
        atomicAdd(p + 3, w * g[3]);
      }
    }
  }
  __syncthreads();

  // ---- MFMA contraction: wave wv owns bins [8*wv, 8*wv+8) ----
  f32x4 acc0 = {0.f, 0.f, 0.f, 0.f};          // cout 0..15
  f32x4 acc1 = {0.f, 0.f, 0.f, 0.f};          // cout 16..31
  {
    int v16 = lane & 15;                      // A row (rows 4-15 dup of 0-3)
    int q   = lane >> 4;
    const char* arow = smem + (size_t)(v16 & 3) * VROWB;
    #pragma unroll
    for (int b = 0; b < 8; ++b) {
      int bin = (wv << 3) + b;
      const float* ap = (const float*)(arow + (bin << 7) + (q << 5));
      f32x4 a0 = *(const f32x4*)ap;           // ch k0..k0+3
      f32x4 a1 = *(const f32x4*)(ap + 4);     // ch k0+4..k0+7
      short8 ahi, alo;
      #pragma unroll
      for (int j = 0; j < 4; ++j) {
        unsigned u0 = __float_as_uint(a0[j]);
        ahi[j] = (short)(u0 >> 16);
        float r0 = a0[j] - __uint_as_float(u0 & 0xFFFF0000u);
        alo[j] = (short)(__float_as_uint(r0) >> 16);
        unsigned u1 = __float_as_uint(a1[j]);
        ahi[j + 4] = (short)(u1 >> 16);
        float r1 = a1[j] - __uint_as_float(u1 & 0xFFFF0000u);
        alo[j + 4] = (short)(__float_as_uint(r1) >> 16);
      }
      int krow = (bin << 5) + (q << 3);       // kappa base for this lane
      {
        int d = v16;
        short8 wh = *(const short8*)(wt_hi + d * 2048 + krow);
        short8 wl = *(const short8*)(wt_lo + d * 2048 + krow);
        acc0 = __builtin_amdgcn_mfma_f32_16x16x32_bf16(ahi, wh, acc0, 0, 0, 0);
        acc0 = __builtin_amdgcn_mfma_f32_16x16x32_bf16(ahi, wl, acc0, 0, 0, 0);
        acc0 = __builtin_amdgcn_mfma_f32_16x16x32_bf16(alo, wh, acc0, 0, 0, 0);
      }
      {
        int d = v16 + 16;
        short8 wh = *(const short8*)(wt_hi + d * 2048 + krow);
        short8 wl = *(const short8*)(wt_lo + d * 2048 + krow);
        acc1 = __builtin_amdgcn_mfma_f32_16x16x32_bf16(ahi, wh, acc1, 0, 0, 0);
        acc1 = __builtin_amdgcn_mfma_f32_16x16x32_bf16(ahi, wl, acc1, 0, 0, 0);
        acc1 = __builtin_amdgcn_mfma_f32_16x16x32_bf16(alo, wh, acc1, 0, 0, 0);
      }
    }
  }

  // ---- per-wave partials: valid C rows 0..3 live in lanes 0..15, regs 0..3
  // C/D layout: col = lane&15 (cout), row = (lane>>4)*4 + reg (voxel)
  if (lane < 16) {
    float* yp = Yp + (wv << 7);               // 4 v x 32 d per wave
    #pragma unroll
    for (int r = 0; r < 4; ++r) {
      yp[r * 32 + lane]      = acc0[r];
      yp[r * 32 + 16 + lane] = acc1[r];
    }
  }
  __syncthreads();

  // ---- reduce 8 wave-partials, normalize, bias, relu, store ----
  if (tid < EPW) {
    float s = 0.f;
    #pragma unroll
    for (int w = 0; w < 8; ++w) s += Yp[(w << 7) + tid];
    int v = tid >> 5;
    int d = tid & 31;
    float dn = fmaxf(den[v], 1e-8f);
    float y = s / dn + bias[d];
    out[(wg << 7) + tid] = fmaxf(y, 0.f);
  }
}

extern "C" void kernel_launch(void* const* d_in, const int* in_sizes, int n_in,
                              void* d_out, int out_size, void* d_ws, size_t ws_size,
                              hipStream_t stream) {
  const float* feats        = (const float*)d_in[0];
  const float* inp_points   = (const float*)d_in[1];
  const float* out_points   = (const float*)d_in[2];
  const float* out_extents  = (const float*)d_in[3];
  const float* scale_compat = (const float*)d_in[4];
  const int*   nbr_idx      = (const int*)d_in[5];
  const int*   row_splits   = (const int*)d_in[6];
  const float* nbr_dist     = (const float*)d_in[7];
  const float* W            = (const float*)d_in[8];
  const float* bias         = (const float*)d_in[9];

  u16* wt_hi = (u16*)d_ws;              // [32][2048] bf16
  u16* wt_lo = wt_hi + 2048 * 32;       // [32][2048] bf16

  static_assert(SMEM_BYTES <= 40960, "LDS over 4-per-CU budget");
  (void)hipFuncSetAttribute((const void*)cconv_kernel,
                            hipFuncAttributeMaxDynamicSharedMemorySize,
                            SMEM_BYTES);

  prep_w_kernel<<<256, 256, 0, stream>>>(W, wt_hi, wt_lo);
  cconv_kernel<<<NWG, THREADS, SMEM_BYTES, stream>>>(
      feats, inp_points, out_points, out_extents, scale_compat, nbr_idx,
      row_splits, nbr_dist, bias, wt_hi, wt_lo, (float*)d_out);
}

// Round 5
// 637.422 us; speedup vs baseline: 1.4095x; 1.0010x over previous
//
#include <hip/hip_runtime.h>
#include <hip/hip_bf16.h>

// Continuous convolution, single-pass fused design (round 4):
//   WG = 4 voxels (128 edges), 512 threads, LDS ~38 KB -> 4 WG/CU (32 waves).
//   Gather: float4 per thread (4 ch of one edge), 2 independent loads issued
//   before the atomic loop. Corner deltas recomputed from a bitmask (no dlt
//   array). den via shfl reduction (fixes r3 zero-vs-atomic race).
//   Contraction: bf16 hi/lo split MFMA (3 products) vs pre-split W^T tables.

typedef unsigned short u16;
typedef unsigned int   u32;
typedef __attribute__((ext_vector_type(4))) float f32x4;
typedef __attribute__((ext_vector_type(8))) short short8;

#define NOUT    65536
#define VX      4               // voxels per WG
#define THREADS 512
#define EPW     128             // edges per WG
#define NWG     (NOUT / VX)     // 16384
#define BSTRIDE 2052            // f32 words per voxel (64 bins * 32 ch + 4 pad)
#define VROWB   (BSTRIDE * 4)   // 8208 bytes
#define BL_BYTES (VX * VROWB)   // 32832

// LDS carve (bytes):
#define OFF_W   BL_BYTES              // wls [8][128] f32  (alias Yp 4KB)
#define OFF_BCA (OFF_W + 8*EPW*4)     // bca [128] u32 (bb | mask<<16 | nc<<24)
#define OFF_FB  (OFF_BCA + EPW*4)     // fbase [128] int
#define OFF_DEN (OFF_FB + EPW*4)      // den [4] f32
#define SMEM_BYTES (OFF_DEN + 16)     // 37968

// ---- prep: split W (2048x32 f32) into transposed bf16 hi/lo tables ----
__global__ void prep_w_kernel(const float* __restrict__ W,
                              u16* __restrict__ wt_hi,
                              u16* __restrict__ wt_lo) {
  int t  = blockIdx.x * 256 + threadIdx.x;   // 0..65535
  int kr = t >> 5;                           // kappa = bin*32 + c
  int d  = t & 31;                           // cout
  float w = W[t];
  unsigned u = __float_as_uint(w);
  u16 hi = (u16)(u >> 16);                              // truncated bf16
  float rem = w - __uint_as_float(u & 0xFFFF0000u);     // exact residual
  u16 lo = (u16)(__float_as_uint(rem) >> 16);
  wt_hi[d * 2048 + kr] = hi;   // W^T: [cout][kappa]
  wt_lo[d * 2048 + kr] = lo;
}

__launch_bounds__(THREADS, 8)   // force VGPR<=64 so 4 WGs/CU fit wave slots
__global__ void cconv_kernel(const float* __restrict__ feats,
                             const float* __restrict__ inp_points,
                             const float* __restrict__ out_points,
                             const float* __restrict__ out_extents,
                             const float* __restrict__ scale_compat,
                             const int*   __restrict__ nbr_idx,
                             const int*   __restrict__ row_splits,
                             const float* __restrict__ nbr_dist,
                             const float* __restrict__ bias,
                             const u16*   __restrict__ wt_hi,
                             const u16*   __restrict__ wt_lo,
                             float*       __restrict__ out) {
  extern __shared__ __align__(16) char smem[];
  float* wls   = (float*)(smem + OFF_W);
  float* Yp    = wls;                         // alias after scatter done
  u32*   bca   = (u32*)(smem + OFF_BCA);
  int*   fbase = (int*)(smem + OFF_FB);
  float* den   = (float*)(smem + OFF_DEN);

  const int tid  = threadIdx.x;
  const int wg   = blockIdx.x;
  const int lane = tid & 63;
  const int wv   = tid >> 6;                  // wave 0..7

  // ---- zero B tile (all threads) ----
  {
    f32x4 z = {0.f, 0.f, 0.f, 0.f};
    for (int i = tid; i < (BL_BYTES / 16); i += THREADS)
      ((f32x4*)smem)[i] = z;
  }

  // ---- geometry: one edge per thread (threads 0..127) ----
  if (tid < EPW) {
    const bool is64 = (row_splits[1] == 0);   // int32 view of int64 splits
    int e  = tid;
    int v  = e >> 5;
    int gv = (wg << 2) + v;
    int ge = (wg << 7) + e;
    int idx = nbr_idx[is64 ? (ge << 1) : ge];
    float dist = nbr_dist[ge];
    float sc   = scale_compat[ge];
    float om = 1.f - dist * dist;
    om = fminf(fmaxf(om, 0.f), 1.f);
    float a = sc * om * om * om;
    float inv = 2.f / out_extents[0];
    float ox = out_points[gv * 3 + 0];
    float oy = out_points[gv * 3 + 1];
    float oz = out_points[gv * 3 + 2];
    float rx = (inp_points[idx * 3 + 0] - ox) * inv;
    float ry = (inp_points[idx * 3 + 1] - oy) * inv;
    float rz = (inp_points[idx * 3 + 2] - oz) * inv;
    float n2   = sqrtf(rx * rx + ry * ry + rz * rz + 1e-12f);
    float ninf = fmaxf(fabsf(rx), fmaxf(fabsf(ry), fabsf(rz)));
    float scl  = (ninf > 1e-8f) ? (n2 / ninf) : 0.f;
    float cx = fminf(fmaxf(rx * scl, -1.f), 1.f);
    float cy = fminf(fmaxf(ry * scl, -1.f), 1.f);
    float cz = fminf(fmaxf(rz * scl, -1.f), 1.f);
    float ux = fminf(fmaxf((cx + 1.f) * 1.5f, 0.f), 3.f);
    float uy = fminf(fmaxf((cy + 1.f) * 1.5f, 0.f), 3.f);
    float uz = fminf(fmaxf((cz + 1.f) * 1.5f, 0.f), 3.f);
    float fx = fminf(floorf(ux), 2.f);
    float fy = fminf(floorf(uy), 2.f);
    float fz = fminf(floorf(uz), 2.f);
    float tx = ux - fx, ty = uy - fy, tz = uz - fz;
    int ix = (int)fx, iy = (int)fy, iz = (int)fz;
    float X1 = tx * a, X0 = a - X1;           // fold importance into x weights
    float Y1 = ty,     Y0 = 1.f - ty;
    float Z1 = tz,     Z0 = 1.f - tz;
    float p00 = X0 * Y0, p01 = X0 * Y1, p10 = X1 * Y0, p11 = X1 * Y1;
    float wc[8];
    wc[0] = p00 * Z0; wc[1] = p00 * Z1; wc[2] = p01 * Z0; wc[3] = p01 * Z1;
    wc[4] = p10 * Z0; wc[5] = p10 * Z1; wc[6] = p11 * Z0; wc[7] = p11 * Z1;
    int kb = (ix * 4 + iy) * 4 + iz;          // base bin (<=42)
    u32 bb = (u32)(v * VROWB + (kb << 7));    // < 32768
    int nc = 0; u32 mask = 0;
    #pragma unroll
    for (int k = 0; k < 8; ++k) {
      if (wc[k] != 0.f) {
        wls[nc * EPW + e] = wc[k];
        mask |= (1u << k);
        ++nc;
      }
    }
    bca[e]   = bb | (mask << 16) | ((u32)nc << 24);
    fbase[e] = idx << 5;
    // per-voxel denom: half-wave (32 lanes = 1 voxel) shuffle reduction
    float s = a;
    s += __shfl_xor(s, 1);
    s += __shfl_xor(s, 2);
    s += __shfl_xor(s, 4);
    s += __shfl_xor(s, 8);
    s += __shfl_xor(s, 16);
    if ((lane & 31) == 0) den[v] = s;
  }
  __syncthreads();

  // ---- scatter: item = (edge, 4-channel group); 2 items per thread ----
  {
    const int c4 = (tid & 7) << 2;            // channel group base
    const int eA = (tid >> 3);                // 0..63
    const int eB = eA + 64;
    u32 mA = bca[eA], mB = bca[eB];
    int fA = fbase[eA], fB = fbase[eB];
    f32x4 gA = *(const f32x4*)&feats[fA + c4];    // both loads in flight
    f32x4 gB = *(const f32x4*)&feats[fB + c4];
    #pragma unroll 2
    for (int it = 0; it < 2; ++it) {
      int   e    = it ? eB : eA;
      u32   m    = it ? mB : mA;
      f32x4 g    = it ? gB : gA;
      u32   base = (m & 0xFFFFu) + ((u32)c4 << 2);
      u32   mask = (m >> 16) & 0xFFu;
      int   nc   = (int)(m >> 24);
      for (int j = 0; j < nc; ++j) {          // ~2-3 iters, uniform per edge
        float w = wls[j * EPW + e];
        int   k = __builtin_ctz(mask);
        mask &= mask - 1;
        u32 d = ((k & 1) << 7) | ((k & 2) << 8) | ((k & 4) << 9);
        float* p = (float*)(smem + base + d);
        atomicAdd(p + 0, w * g[0]);
        atomicAdd(p + 1, w * g[1]);
        atomicAdd(p + 2, w * g[2]);
        atomicAdd(p + 3, w * g[3]);
      }
    }
  }
  __syncthreads();

  // ---- MFMA contraction: wave wv owns bins [8*wv, 8*wv+8) ----
  f32x4 acc0 = {0.f, 0.f, 0.f, 0.f};          // cout 0..15
  f32x4 acc1 = {0.f, 0.f, 0.f, 0.f};          // cout 16..31
  {
    int v16 = lane & 15;                      // A row (rows 4-15 dup of 0-3)
    int q   = lane >> 4;
    const char* arow = smem + (size_t)(v16 & 3) * VROWB;
    #pragma unroll
    for (int b = 0; b < 8; ++b) {
      int bin = (wv << 3) + b;
      const float* ap = (const float*)(arow + (bin << 7) + (q << 5));
      f32x4 a0 = *(const f32x4*)ap;           // ch k0..k0+3
      f32x4 a1 = *(const f32x4*)(ap + 4);     // ch k0+4..k0+7
      short8 ahi, alo;
      #pragma unroll
      for (int j = 0; j < 4; ++j) {
        unsigned u0 = __float_as_uint(a0[j]);
        ahi[j] = (short)(u0 >> 16);
        float r0 = a0[j] - __uint_as_float(u0 & 0xFFFF0000u);
        alo[j] = (short)(__float_as_uint(r0) >> 16);
        unsigned u1 = __float_as_uint(a1[j]);
        ahi[j + 4] = (short)(u1 >> 16);
        float r1 = a1[j] - __uint_as_float(u1 & 0xFFFF0000u);
        alo[j + 4] = (short)(__float_as_uint(r1) >> 16);
      }
      int krow = (bin << 5) + (q << 3);       // kappa base for this lane
      {
        int d = v16;
        short8 wh = *(const short8*)(wt_hi + d * 2048 + krow);
        short8 wl = *(const short8*)(wt_lo + d * 2048 + krow);
        acc0 = __builtin_amdgcn_mfma_f32_16x16x32_bf16(ahi, wh, acc0, 0, 0, 0);
        acc0 = __builtin_amdgcn_mfma_f32_16x16x32_bf16(ahi, wl, acc0, 0, 0, 0);
        acc0 = __builtin_amdgcn_mfma_f32_16x16x32_bf16(alo, wh, acc0, 0, 0, 0);
      }
      {
        int d = v16 + 16;
        short8 wh = *(const short8*)(wt_hi + d * 2048 + krow);
        short8 wl = *(const short8*)(wt_lo + d * 2048 + krow);
        acc1 = __builtin_amdgcn_mfma_f32_16x16x32_bf16(ahi, wh, acc1, 0, 0, 0);
        acc1 = __builtin_amdgcn_mfma_f32_16x16x32_bf16(ahi, wl, acc1, 0, 0, 0);
        acc1 = __builtin_amdgcn_mfma_f32_16x16x32_bf16(alo, wh, acc1, 0, 0, 0);
      }
    }
  }

  // ---- per-wave partials: valid C rows 0..3 live in lanes 0..15, regs 0..3
  // C/D layout: col = lane&15 (cout), row = (lane>>4)*4 + reg (voxel)
  if (lane < 16) {
    float* yp = Yp + (wv << 7);               // 4 v x 32 d per wave
    #pragma unroll
    for (int r = 0; r < 4; ++r) {
      yp[r * 32 + lane]      = acc0[r];
      yp[r * 32 + 16 + lane] = acc1[r];
    }
  }
  __syncthreads();

  // ---- reduce 8 wave-partials, normalize, bias, relu, store ----
  if (tid < EPW) {
    float s = 0.f;
    #pragma unroll
    for (int w = 0; w < 8; ++w) s += Yp[(w << 7) + tid];
    int v = tid >> 5;
    int d = tid & 31;
    float dn = fmaxf(den[v], 1e-8f);
    float y = s / dn + bias[d];
    out[(wg << 7) + tid] = fmaxf(y, 0.f);
  }
}

extern "C" void kernel_launch(void* const* d_in, const int* in_sizes, int n_in,
                              void* d_out, int out_size, void* d_ws, size_t ws_size,
                              hipStream_t stream) {
  const float* feats        = (const float*)d_in[0];
  const float* inp_points   = (const float*)d_in[1];
  const float* out_points   = (const float*)d_in[2];
  const float* out_extents  = (const float*)d_in[3];
  const float* scale_compat = (const float*)d_in[4];
  const int*   nbr_idx      = (const int*)d_in[5];
  const int*   row_splits   = (const int*)d_in[6];
  const float* nbr_dist     = (const float*)d_in[7];
  const float* W            = (const float*)d_in[8];
  const float* bias         = (const float*)d_in[9];

  u16* wt_hi = (u16*)d_ws;              // [32][2048] bf16
  u16* wt_lo = wt_hi + 2048 * 32;       // [32][2048] bf16

  static_assert(SMEM_BYTES <= 40960, "LDS over 4-per-CU budget");
  (void)hipFuncSetAttribute((const void*)cconv_kernel,
                            hipFuncAttributeMaxDynamicSharedMemorySize,
                            SMEM_BYTES);

  prep_w_kernel<<<256, 256, 0, stream>>>(W, wt_hi, wt_lo);
  cconv_kernel<<<NWG, THREADS, SMEM_BYTES, stream>>>(
      feats, inp_points, out_points, out_extents, scale_compat, nbr_idx,
      row_splits, nbr_dist, bias, wt_hi, wt_lo, (float*)d_out);
}

// Round 6
// 617.476 us; speedup vs baseline: 1.4550x; 1.0323x over previous
//
#include <hip/hip_runtime.h>
#include <hip/hip_bf16.h>

// Continuous convolution, single-pass fused design (round 6):
//   WG = 4 voxels (128 edges), 512 threads, LDS ~38 KB -> 4 WG/CU (32 waves).
//   r6 changes vs r5:
//   (1) W pre-packed in MFMA B-fragment order: wpk[table][bin][lane][8] ->
//       each wave W-load is a contiguous 1KB burst (was 64 scattered granules
//       per load = L1-pipe serialization, the r3/r5 675us invariant).
//   (2) scatter lane mapping back to lane=channel (half-wave = one edge row):
//       every LDS atomic hits all 32 banks once per half-wave (r5's mapping
//       was 8-way conflicted: corner bases are 128B-aligned). Gathers are
//       still prefetched: 8 independent coalesced row-loads before atomics.
//   Contraction: bf16 hi/lo split MFMA (3 products), f32-exact to ~2^-16.

typedef unsigned short u16;
typedef unsigned int   u32;
typedef __attribute__((ext_vector_type(4))) float f32x4;
typedef __attribute__((ext_vector_type(8))) short short8;

#define NOUT    65536
#define VX      4               // voxels per WG
#define THREADS 512
#define EPW     128             // edges per WG
#define NWG     (NOUT / VX)     // 16384
#define BSTRIDE 2052            // f32 words per voxel (64 bins * 32 ch + 4 pad)
#define VROWB   (BSTRIDE * 4)   // 8208 bytes
#define BL_BYTES (VX * VROWB)   // 32832

// LDS carve (bytes):
#define OFF_W   BL_BYTES              // wls [8][128] f32  (alias Yp 4KB)
#define OFF_BCA (OFF_W + 8*EPW*4)     // bca [128] u32 (bb | mask<<16 | nc<<24)
#define OFF_FB  (OFF_BCA + EPW*4)     // fbase [128] int
#define OFF_DEN (OFF_FB + EPW*4)      // den [4] f32
#define SMEM_BYTES (OFF_DEN + 16)     // 37968

// ---- prep: pack W (2048x32 f32) into MFMA B-fragment order, bf16 hi/lo ----
// wpk[tb][bin][lane][j] u16, tb: 0=hi d0-15, 1=lo d0-15, 2=hi d16-31, 3=lo.
// Fragment: lane l supplies B[kappa = bin*32 + (l>>4)*8 + j][d = (l&15)+16*(tb>>1)].
__global__ void prep_w_kernel(const float* __restrict__ W,
                              u16* __restrict__ wpk) {
  int id  = blockIdx.x * 256 + threadIdx.x;   // 0..131071
  int j   = id & 7;
  int l   = (id >> 3) & 63;
  int bin = (id >> 9) & 63;
  int tb  = id >> 15;                         // 0..3
  int kap = (bin << 5) + ((l >> 4) << 3) + j;
  int d   = (l & 15) + ((tb >> 1) << 4);
  float w = W[kap * 32 + d];
  unsigned u = __float_as_uint(w);
  u16 val;
  if (tb & 1) {
    float rem = w - __uint_as_float(u & 0xFFFF0000u);   // exact residual
    val = (u16)(__float_as_uint(rem) >> 16);
  } else {
    val = (u16)(u >> 16);                               // truncated bf16
  }
  wpk[id] = val;
}

__launch_bounds__(THREADS, 8)   // VGPR<=64 so 4 WGs/CU fit wave slots
__global__ void cconv_kernel(const float* __restrict__ feats,
                             const float* __restrict__ inp_points,
                             const float* __restrict__ out_points,
                             const float* __restrict__ out_extents,
                             const float* __restrict__ scale_compat,
                             const int*   __restrict__ nbr_idx,
                             const int*   __restrict__ row_splits,
                             const float* __restrict__ nbr_dist,
                             const float* __restrict__ bias,
                             const u16*   __restrict__ wpk,
                             float*       __restrict__ out) {
  extern __shared__ __align__(16) char smem[];
  float* wls   = (float*)(smem + OFF_W);
  float* Yp    = wls;                         // alias after scatter done
  u32*   bca   = (u32*)(smem + OFF_BCA);
  int*   fbase = (int*)(smem + OFF_FB);
  float* den   = (float*)(smem + OFF_DEN);

  const int tid  = threadIdx.x;
  const int wg   = blockIdx.x;
  const int lane = tid & 63;
  const int wv   = tid >> 6;                  // wave 0..7

  // ---- zero B tile (all threads) ----
  {
    f32x4 z = {0.f, 0.f, 0.f, 0.f};
    for (int i = tid; i < (BL_BYTES / 16); i += THREADS)
      ((f32x4*)smem)[i] = z;
  }

  // ---- geometry: one edge per thread (threads 0..127) ----
  if (tid < EPW) {
    const bool is64 = (row_splits[1] == 0);   // int32 view of int64 splits
    int e  = tid;
    int v  = e >> 5;
    int gv = (wg << 2) + v;
    int ge = (wg << 7) + e;
    int idx = nbr_idx[is64 ? (ge << 1) : ge];
    float dist = nbr_dist[ge];
    float sc   = scale_compat[ge];
    float om = 1.f - dist * dist;
    om = fminf(fmaxf(om, 0.f), 1.f);
    float a = sc * om * om * om;
    float inv = 2.f / out_extents[0];
    float ox = out_points[gv * 3 + 0];
    float oy = out_points[gv * 3 + 1];
    float oz = out_points[gv * 3 + 2];
    float rx = (inp_points[idx * 3 + 0] - ox) * inv;
    float ry = (inp_points[idx * 3 + 1] - oy) * inv;
    float rz = (inp_points[idx * 3 + 2] - oz) * inv;
    float n2   = sqrtf(rx * rx + ry * ry + rz * rz + 1e-12f);
    float ninf = fmaxf(fabsf(rx), fmaxf(fabsf(ry), fabsf(rz)));
    float scl  = (ninf > 1e-8f) ? (n2 / ninf) : 0.f;
    float cx = fminf(fmaxf(rx * scl, -1.f), 1.f);
    float cy = fminf(fmaxf(ry * scl, -1.f), 1.f);
    float cz = fminf(fmaxf(rz * scl, -1.f), 1.f);
    float ux = fminf(fmaxf((cx + 1.f) * 1.5f, 0.f), 3.f);
    float uy = fminf(fmaxf((cy + 1.f) * 1.5f, 0.f), 3.f);
    float uz = fminf(fmaxf((cz + 1.f) * 1.5f, 0.f), 3.f);
    float fx = fminf(floorf(ux), 2.f);
    float fy = fminf(floorf(uy), 2.f);
    float fz = fminf(floorf(uz), 2.f);
    float tx = ux - fx, ty = uy - fy, tz = uz - fz;
    int ix = (int)fx, iy = (int)fy, iz = (int)fz;
    float X1 = tx * a, X0 = a - X1;           // fold importance into x weights
    float Y1 = ty,     Y0 = 1.f - ty;
    float Z1 = tz,     Z0 = 1.f - tz;
    float p00 = X0 * Y0, p01 = X0 * Y1, p10 = X1 * Y0, p11 = X1 * Y1;
    float wc[8];
    wc[0] = p00 * Z0; wc[1] = p00 * Z1; wc[2] = p01 * Z0; wc[3] = p01 * Z1;
    wc[4] = p10 * Z0; wc[5] = p10 * Z1; wc[6] = p11 * Z0; wc[7] = p11 * Z1;
    int kb = (ix * 4 + iy) * 4 + iz;          // base bin (<=42)
    u32 bb = (u32)(v * VROWB + (kb << 7));    // < 32768
    int nc = 0; u32 mask = 0;
    #pragma unroll
    for (int k = 0; k < 8; ++k) {
      if (wc[k] != 0.f) {
        wls[nc * EPW + e] = wc[k];
        mask |= (1u << k);
        ++nc;
      }
    }
    bca[e]   = bb | (mask << 16) | ((u32)nc << 24);
    fbase[e] = idx << 5;
    // per-voxel denom: half-wave (32 lanes = 1 voxel) shuffle reduction
    float s = a;
    s += __shfl_xor(s, 1);
    s += __shfl_xor(s, 2);
    s += __shfl_xor(s, 4);
    s += __shfl_xor(s, 8);
    s += __shfl_xor(s, 16);
    if ((lane & 31) == 0) den[v] = s;
  }
  __syncthreads();

  // ---- scatter: lane=channel, half-wave=edge row; 8 edges per thread ----
  {
    const int c  = tid & 31;                  // channel
    const int e0 = tid >> 5;                  // 0..15
    u32 bcn[8]; int fbs[8]; float fg[8];
    #pragma unroll
    for (int it = 0; it < 8; ++it) {
      int e = (it << 4) + e0;
      bcn[it] = bca[e];
      fbs[it] = fbase[e];
    }
    #pragma unroll
    for (int it = 0; it < 8; ++it)            // 8 independent coalesced loads
      fg[it] = feats[fbs[it] + c];
    #pragma unroll
    for (int it = 0; it < 8; ++it) {
      int   e    = (it << 4) + e0;
      u32   m    = bcn[it];
      u32   base = (m & 0xFFFFu) + ((u32)c << 2);
      u32   mask = (m >> 16) & 0xFFu;
      int   nc   = (int)(m >> 24);
      float f    = fg[it];
      for (int j = 0; j < nc; ++j) {          // ~2-3 iters, uniform per edge
        float w = wls[j * EPW + e];           // broadcast within half-wave
        int   k = __builtin_ctz(mask);
        mask &= mask - 1;
        u32 d = ((k & 1) << 7) | ((k & 2) << 8) | ((k & 4) << 9);
        atomicAdd((float*)(smem + base + d), w * f);  // banks 0..31, <=2-way
      }
    }
  }
  __syncthreads();

  // ---- MFMA contraction: wave wv owns bins [8*wv, 8*wv+8) ----
  f32x4 acc0 = {0.f, 0.f, 0.f, 0.f};          // cout 0..15
  f32x4 acc1 = {0.f, 0.f, 0.f, 0.f};          // cout 16..31
  {
    const short8* wp = (const short8*)wpk;    // [4][64][64] fragments
    int v16 = lane & 15;                      // A row (rows 4-15 dup of 0-3)
    int q   = lane >> 4;
    const char* arow = smem + (size_t)(v16 & 3) * VROWB;
    #pragma unroll
    for (int b = 0; b < 8; ++b) {
      int bin = (wv << 3) + b;
      // coalesced 1KB-burst B-fragment loads (L2-resident)
      short8 w0h = wp[((0 * 64 + bin) << 6) + lane];
      short8 w0l = wp[((1 * 64 + bin) << 6) + lane];
      short8 w1h = wp[((2 * 64 + bin) << 6) + lane];
      short8 w1l = wp[((3 * 64 + bin) << 6) + lane];
      const float* ap = (const float*)(arow + (bin << 7) + (q << 5));
      f32x4 a0 = *(const f32x4*)ap;           // ch k0..k0+3
      f32x4 a1 = *(const f32x4*)(ap + 4);     // ch k0+4..k0+7
      short8 ahi, alo;
      #pragma unroll
      for (int j = 0; j < 4; ++j) {
        unsigned u0 = __float_as_uint(a0[j]);
        ahi[j] = (short)(u0 >> 16);
        float r0 = a0[j] - __uint_as_float(u0 & 0xFFFF0000u);
        alo[j] = (short)(__float_as_uint(r0) >> 16);
        unsigned u1 = __float_as_uint(a1[j]);
        ahi[j + 4] = (short)(u1 >> 16);
        float r1 = a1[j] - __uint_as_float(u1 & 0xFFFF0000u);
        alo[j + 4] = (short)(__float_as_uint(r1) >> 16);
      }
      acc0 = __builtin_amdgcn_mfma_f32_16x16x32_bf16(ahi, w0h, acc0, 0, 0, 0);
      acc0 = __builtin_amdgcn_mfma_f32_16x16x32_bf16(ahi, w0l, acc0, 0, 0, 0);
      acc0 = __builtin_amdgcn_mfma_f32_16x16x32_bf16(alo, w0h, acc0, 0, 0, 0);
      acc1 = __builtin_amdgcn_mfma_f32_16x16x32_bf16(ahi, w1h, acc1, 0, 0, 0);
      acc1 = __builtin_amdgcn_mfma_f32_16x16x32_bf16(ahi, w1l, acc1, 0, 0, 0);
      acc1 = __builtin_amdgcn_mfma_f32_16x16x32_bf16(alo, w1h, acc1, 0, 0, 0);
    }
  }

  // ---- per-wave partials: valid C rows 0..3 live in lanes 0..15, regs 0..3
  // C/D layout: col = lane&15 (cout), row = (lane>>4)*4 + reg (voxel)
  if (lane < 16) {
    float* yp = Yp + (wv << 7);               // 4 v x 32 d per wave
    #pragma unroll
    for (int r = 0; r < 4; ++r) {
      yp[r * 32 + lane]      = acc0[r];
      yp[r * 32 + 16 + lane] = acc1[r];
    }
  }
  __syncthreads();

  // ---- reduce 8 wave-partials, normalize, bias, relu, store ----
  if (tid < EPW) {
    float s = 0.f;
    #pragma unroll
    for (int w = 0; w < 8; ++w) s += Yp[(w << 7) + tid];
    int v = tid >> 5;
    int d = tid & 31;
    float dn = fmaxf(den[v], 1e-8f);
    float y = s / dn + bias[d];
    out[(wg << 7) + tid] = fmaxf(y, 0.f);
  }
}

extern "C" void kernel_launch(void* const* d_in, const int* in_sizes, int n_in,
                              void* d_out, int out_size, void* d_ws, size_t ws_size,
                              hipStream_t stream) {
  const float* feats        = (const float*)d_in[0];
  const float* inp_points   = (const float*)d_in[1];
  const float* out_points   = (const float*)d_in[2];
  const float* out_extents  = (const float*)d_in[3];
  const float* scale_compat = (const float*)d_in[4];
  const int*   nbr_idx      = (const int*)d_in[5];
  const int*   row_splits   = (const int*)d_in[6];
  const float* nbr_dist     = (const float*)d_in[7];
  const float* W            = (const float*)d_in[8];
  const float* bias         = (const float*)d_in[9];

  u16* wpk = (u16*)d_ws;                // [4][64][64][8] u16 = 256 KiB

  static_assert(SMEM_BYTES <= 40960, "LDS over 4-per-CU budget");
  (void)hipFuncSetAttribute((const void*)cconv_kernel,
                            hipFuncAttributeMaxDynamicSharedMemorySize,
                            SMEM_BYTES);

  prep_w_kernel<<<512, 256, 0, stream>>>(W, wpk);
  cconv_kernel<<<NWG, THREADS, SMEM_BYTES, stream>>>(
      feats, inp_points, out_points, out_extents, scale_compat, nbr_idx,
      row_splits, nbr_dist, bias, wpk, (float*)d_out);
}